// Round 4
// baseline (173.046 us; speedup 1.0000x reference)
//
#include <hip/hip_runtime.h>
#include <hip/hip_bf16.h>
#include <math.h>

#define CHN 192
#define BATCHN 65536
#define NBLOCKS 4096
#define ROWS_PER_BLOCK (BATCHN / NBLOCKS)   // 16

// ---- fast device math -------------------------------------------------------
__device__ __forceinline__ float fast_rcp(float x)  { return __builtin_amdgcn_rcpf(x); }

// Opaque register pin (kept from r3; harmless, guards against remat/sink).
__device__ __forceinline__ void pin(float& v) { asm volatile("" : "+v"(v)); }

// accurate softplus for the once-per-block weight transform
__device__ __forceinline__ float softplus_acc(float h) {
    if (h > 20.0f) return h;
    return log1pf(expf(h));
}

// ---- rational tanh (Eigen coefficients), PAIRED: 2 tanhs share ONE v_rcp ----
// tanh(t) ~= t*P(t^2)/Q(t^2), |t| clamped to 7.9053; err ~1e-7.
// Pairing: r = rcp(Qp*Qm); yp = tp*Pp*Qm*r; ym = tm*Pm*Qp*r.
#define TCLAMP 7.90531110763549805f
#define A1  4.89352455891786e-03f
#define A3  6.37261928875436e-04f
#define A5  1.48572235717979e-05f
#define A7  5.12229709037114e-08f
#define A9  -8.60467152213735e-11f
#define A11 2.00018790482477e-13f
#define A13 -2.76076847742355e-16f
#define B0  4.89352518554385e-03f
#define B2  2.26843463243900e-03f
#define B4  1.18534705686654e-04f
#define B6  1.19825839466702e-06f

__device__ __forceinline__ void tanh2(float tp_in, float tm_in, float& yp, float& ym) {
    float tp = fminf(fmaxf(tp_in, -TCLAMP), TCLAMP);
    float tm = fminf(fmaxf(tm_in, -TCLAMP), TCLAMP);
    float up = tp * tp, um = tm * tm;
    float Pp = fmaf(up, A13, A11);
    float Pm = fmaf(um, A13, A11);
    Pp = fmaf(up, Pp, A9);  Pm = fmaf(um, Pm, A9);
    Pp = fmaf(up, Pp, A7);  Pm = fmaf(um, Pm, A7);
    Pp = fmaf(up, Pp, A5);  Pm = fmaf(um, Pm, A5);
    Pp = fmaf(up, Pp, A3);  Pm = fmaf(um, Pm, A3);
    Pp = fmaf(up, Pp, A1);  Pm = fmaf(um, Pm, A1);
    float Qp = fmaf(up, B6, B4);
    float Qm = fmaf(um, B6, B4);
    Qp = fmaf(up, Qp, B2);  Qm = fmaf(um, Qm, B2);
    Qp = fmaf(up, Qp, B0);  Qm = fmaf(um, Qm, B0);
    float np = tp * Pp, nm = tm * Pm;
    float r  = fast_rcp(Qp * Qm);           // ONE trans op for both tanhs
    yp = np * Qm * r;
    ym = nm * Qp * r;
}

// ---- per-channel weights (plain domain, 43 floats) --------------------------
struct WReg {
    float W0[3], B0c[3], T0[3];
    float W1[9], B1c[3], T1[3];
    float W2[9], B2c[3], T2[3];
    float W3[3], b3;
};

__device__ __forceinline__ float density_pair(const WReg& w, float xv) {
    float xp = xv + 0.5f, xm = xv - 0.5f;
    float vp[3], vm[3];
#pragma unroll
    for (int i = 0; i < 3; ++i) {
        float tp = fmaf(w.W0[i], xp, w.B0c[i]);
        float tm = fmaf(w.W0[i], xm, w.B0c[i]);
        float yp, ym; tanh2(tp, tm, yp, ym);
        vp[i] = fmaf(w.T0[i], yp, tp);
        vm[i] = fmaf(w.T0[i], ym, tm);
    }
    float zp[3], zm[3];
#pragma unroll
    for (int p = 0; p < 3; ++p) {
        float tp = w.B1c[p], tm = w.B1c[p];
#pragma unroll
        for (int i = 0; i < 3; ++i) {
            tp = fmaf(vp[i], w.W1[i * 3 + p], tp);
            tm = fmaf(vm[i], w.W1[i * 3 + p], tm);
        }
        float yp, ym; tanh2(tp, tm, yp, ym);
        zp[p] = fmaf(w.T1[p], yp, tp);
        zm[p] = fmaf(w.T1[p], ym, tm);
    }
    float up3[3], um3[3];
#pragma unroll
    for (int p = 0; p < 3; ++p) {
        float tp = w.B2c[p], tm = w.B2c[p];
#pragma unroll
        for (int i = 0; i < 3; ++i) {
            tp = fmaf(zp[i], w.W2[i * 3 + p], tp);
            tm = fmaf(zm[i], w.W2[i * 3 + p], tm);
        }
        float yp, ym; tanh2(tp, tm, yp, ym);
        up3[p] = fmaf(w.T2[p], yp, tp);
        um3[p] = fmaf(w.T2[p], ym, tm);
    }
    float sp = w.b3, sm = w.b3;
#pragma unroll
    for (int i = 0; i < 3; ++i) {
        sp = fmaf(up3[i], w.W3[i], sp);
        sm = fmaf(um3[i], w.W3[i], sm);
    }
    // sigmoid(sp) - sigmoid(sm) = 0.5*(tanh(sp/2) - tanh(sm/2)), paired too
    float hp, hm; tanh2(0.5f * sp, 0.5f * sm, hp, hm);
    return 0.5f * (hp - hm);
}

__global__ __launch_bounds__(CHN) void density_kernel(
    const float* __restrict__ x,
    const float* __restrict__ a0, const float* __restrict__ a1, const float* __restrict__ a2,
    const float* __restrict__ b0, const float* __restrict__ b1, const float* __restrict__ b2,
    const float* __restrict__ b3,
    const float* __restrict__ H0, const float* __restrict__ H1, const float* __restrict__ H2,
    const float* __restrict__ H3,
    float* __restrict__ out)
{
    const int c = threadIdx.x;          // thread <-> channel

    WReg w;
#pragma unroll
    for (int i = 0; i < 3; ++i) {
        w.T0[i]  = tanhf(a0[c * 3 + i]);
        w.T1[i]  = tanhf(a1[c * 3 + i]);
        w.T2[i]  = tanhf(a2[c * 3 + i]);
        w.B0c[i] = b0[c * 3 + i];
        w.B1c[i] = b1[c * 3 + i];
        w.B2c[i] = b2[c * 3 + i];
        w.W0[i]  = softplus_acc(H0[c * 3 + i]);   // (C,1,3)
        w.W3[i]  = softplus_acc(H3[c * 3 + i]);   // (C,3,1)
    }
#pragma unroll
    for (int i = 0; i < 9; ++i) {
        w.W1[i] = softplus_acc(H1[c * 9 + i]);    // (C,3,3) [i][p]
        w.W2[i] = softplus_acc(H2[c * 9 + i]);
    }
    w.b3 = b3[c];

#pragma unroll
    for (int i = 0; i < 3; ++i) {
        pin(w.W0[i]); pin(w.B0c[i]); pin(w.T0[i]);
        pin(w.B1c[i]); pin(w.T1[i]);
        pin(w.B2c[i]); pin(w.T2[i]);
        pin(w.W3[i]);
    }
#pragma unroll
    for (int i = 0; i < 9; ++i) { pin(w.W1[i]); pin(w.W2[i]); }
    pin(w.b3);

    const int b_start = blockIdx.x * ROWS_PER_BLOCK;
#pragma unroll 4
    for (int r = 0; r < ROWS_PER_BLOCK; ++r) {
        const int idx = (b_start + r) * CHN + c;
        out[idx] = density_pair(w, x[idx]);
    }
}

extern "C" void kernel_launch(void* const* d_in, const int* in_sizes, int n_in,
                              void* d_out, int out_size, void* d_ws, size_t ws_size,
                              hipStream_t stream) {
    const float* x  = (const float*)d_in[0];
    const float* a0 = (const float*)d_in[1];
    const float* a1 = (const float*)d_in[2];
    const float* a2 = (const float*)d_in[3];
    const float* b0 = (const float*)d_in[4];
    const float* b1 = (const float*)d_in[5];
    const float* b2 = (const float*)d_in[6];
    const float* b3 = (const float*)d_in[7];
    const float* H0 = (const float*)d_in[8];
    const float* H1 = (const float*)d_in[9];
    const float* H2 = (const float*)d_in[10];
    const float* H3 = (const float*)d_in[11];
    float* out = (float*)d_out;

    density_kernel<<<NBLOCKS, CHN, 0, stream>>>(x, a0, a1, a2, b0, b1, b2, b3,
                                                H0, H1, H2, H3, out);
}

// Round 5
// 136.454 us; speedup vs baseline: 1.2682x; 1.2682x over previous
//
#include <hip/hip_runtime.h>
#include <hip/hip_bf16.h>
#include <math.h>

#define CHN 192
#define BATCHN 65536
#define NBLOCKS 4096
#define ROWS_PER_BLOCK (BATCHN / NBLOCKS)   // 16
#define NW 43                                // transformed-weight slots per channel

// ---- fast device math -------------------------------------------------------
__device__ __forceinline__ float fast_rcp(float x)  { return __builtin_amdgcn_rcpf(x); }
__device__ __forceinline__ void pin(float& v) { asm volatile("" : "+v"(v)); }

__device__ __forceinline__ float softplus_acc(float h) {
    if (h > 20.0f) return h;
    return log1pf(expf(h));
}

// ---- rational tanh (Eigen coefficients), PAIRED: 2 tanhs share ONE v_rcp ----
#define TCLAMP 7.90531110763549805f
#define A1  4.89352455891786e-03f
#define A3  6.37261928875436e-04f
#define A5  1.48572235717979e-05f
#define A7  5.12229709037114e-08f
#define A9  -8.60467152213735e-11f
#define A11 2.00018790482477e-13f
#define A13 -2.76076847742355e-16f
#define B0  4.89352518554385e-03f
#define B2  2.26843463243900e-03f
#define B4  1.18534705686654e-04f
#define B6  1.19825839466702e-06f

__device__ __forceinline__ void tanh2(float tp_in, float tm_in, float& yp, float& ym) {
    float tp = fminf(fmaxf(tp_in, -TCLAMP), TCLAMP);
    float tm = fminf(fmaxf(tm_in, -TCLAMP), TCLAMP);
    float up = tp * tp, um = tm * tm;
    float Pp = fmaf(up, A13, A11);
    float Pm = fmaf(um, A13, A11);
    Pp = fmaf(up, Pp, A9);  Pm = fmaf(um, Pm, A9);
    Pp = fmaf(up, Pp, A7);  Pm = fmaf(um, Pm, A7);
    Pp = fmaf(up, Pp, A5);  Pm = fmaf(um, Pm, A5);
    Pp = fmaf(up, Pp, A3);  Pm = fmaf(um, Pm, A3);
    Pp = fmaf(up, Pp, A1);  Pm = fmaf(um, Pm, A1);
    float Qp = fmaf(up, B6, B4);
    float Qm = fmaf(um, B6, B4);
    Qp = fmaf(up, Qp, B2);  Qm = fmaf(um, Qm, B2);
    Qp = fmaf(up, Qp, B0);  Qm = fmaf(um, Qm, B0);
    float np = tp * Pp, nm = tm * Pm;
    float r  = fast_rcp(Qp * Qm);           // ONE trans op for both tanhs
    yp = np * Qm * r;
    ym = nm * Qp * r;
}

// ============================================================================
// Kernel A: apply softplus/tanh to weights ONCE, write slot-major to ws.
// ws layout: ws[s*CHN + c], s in [0,43):
//   0-2 W0 | 3-5 B0 | 6-8 T0 | 9-17 W1 | 18-20 B1 | 21-23 T1
//   24-32 W2 | 33-35 B2 | 36-38 T2 | 39-41 W3 | 42 b3
// ============================================================================
__global__ __launch_bounds__(CHN) void weights_kernel(
    const float* __restrict__ a0, const float* __restrict__ a1, const float* __restrict__ a2,
    const float* __restrict__ b0, const float* __restrict__ b1, const float* __restrict__ b2,
    const float* __restrict__ b3,
    const float* __restrict__ H0, const float* __restrict__ H1, const float* __restrict__ H2,
    const float* __restrict__ H3,
    float* __restrict__ ws)
{
    const int c = threadIdx.x;
#pragma unroll
    for (int i = 0; i < 3; ++i) {
        ws[(0  + i) * CHN + c] = softplus_acc(H0[c * 3 + i]);
        ws[(3  + i) * CHN + c] = b0[c * 3 + i];
        ws[(6  + i) * CHN + c] = tanhf(a0[c * 3 + i]);
        ws[(18 + i) * CHN + c] = b1[c * 3 + i];
        ws[(21 + i) * CHN + c] = tanhf(a1[c * 3 + i]);
        ws[(33 + i) * CHN + c] = b2[c * 3 + i];
        ws[(36 + i) * CHN + c] = tanhf(a2[c * 3 + i]);
        ws[(39 + i) * CHN + c] = softplus_acc(H3[c * 3 + i]);
    }
#pragma unroll
    for (int i = 0; i < 9; ++i) {
        ws[(9  + i) * CHN + c] = softplus_acc(H1[c * 9 + i]);
        ws[(24 + i) * CHN + c] = softplus_acc(H2[c * 9 + i]);
    }
    ws[42 * CHN + c] = b3[c];
}

// ============================================================================
// Kernel B: zero libm. Load 43 transformed weights (coalesced, static-indexed
// registers), then a pure-FMA row loop.
// ============================================================================
__device__ __forceinline__ float density_pair(const float* __restrict__ W, float xv) {
    float xp = xv + 0.5f, xm = xv - 0.5f;
    float vp[3], vm[3];
#pragma unroll
    for (int i = 0; i < 3; ++i) {
        float tp = fmaf(W[0 + i], xp, W[3 + i]);
        float tm = fmaf(W[0 + i], xm, W[3 + i]);
        float yp, ym; tanh2(tp, tm, yp, ym);
        vp[i] = fmaf(W[6 + i], yp, tp);
        vm[i] = fmaf(W[6 + i], ym, tm);
    }
    float zp[3], zm[3];
#pragma unroll
    for (int p = 0; p < 3; ++p) {
        float tp = W[18 + p], tm = W[18 + p];
#pragma unroll
        for (int i = 0; i < 3; ++i) {
            tp = fmaf(vp[i], W[9 + i * 3 + p], tp);
            tm = fmaf(vm[i], W[9 + i * 3 + p], tm);
        }
        float yp, ym; tanh2(tp, tm, yp, ym);
        zp[p] = fmaf(W[21 + p], yp, tp);
        zm[p] = fmaf(W[21 + p], ym, tm);
    }
    float up3[3], um3[3];
#pragma unroll
    for (int p = 0; p < 3; ++p) {
        float tp = W[33 + p], tm = W[33 + p];
#pragma unroll
        for (int i = 0; i < 3; ++i) {
            tp = fmaf(zp[i], W[24 + i * 3 + p], tp);
            tm = fmaf(zm[i], W[24 + i * 3 + p], tm);
        }
        float yp, ym; tanh2(tp, tm, yp, ym);
        up3[p] = fmaf(W[36 + p], yp, tp);
        um3[p] = fmaf(W[36 + p], ym, tm);
    }
    float sp = W[42], sm = W[42];
#pragma unroll
    for (int i = 0; i < 3; ++i) {
        sp = fmaf(up3[i], W[39 + i], sp);
        sm = fmaf(um3[i], W[39 + i], sm);
    }
    // sigmoid(sp) - sigmoid(sm) = 0.5*(tanh(sp/2) - tanh(sm/2))
    float hp, hm; tanh2(0.5f * sp, 0.5f * sm, hp, hm);
    return 0.5f * (hp - hm);
}

__global__ __launch_bounds__(CHN, 1) void density_kernel(
    const float* __restrict__ x,
    const float* __restrict__ wt,
    float* __restrict__ out)
{
    const int c = threadIdx.x;          // thread <-> channel

    float W[NW];
#pragma unroll
    for (int s = 0; s < NW; ++s) W[s] = wt[s * CHN + c];   // 43 coalesced dwords
#pragma unroll
    for (int s = 0; s < NW; ++s) pin(W[s]);                // forbid reload/remat

    const int b_start = blockIdx.x * ROWS_PER_BLOCK;
#pragma unroll 2
    for (int r = 0; r < ROWS_PER_BLOCK; ++r) {
        const int idx = (b_start + r) * CHN + c;
        out[idx] = density_pair(W, x[idx]);
    }
}

extern "C" void kernel_launch(void* const* d_in, const int* in_sizes, int n_in,
                              void* d_out, int out_size, void* d_ws, size_t ws_size,
                              hipStream_t stream) {
    const float* x  = (const float*)d_in[0];
    const float* a0 = (const float*)d_in[1];
    const float* a1 = (const float*)d_in[2];
    const float* a2 = (const float*)d_in[3];
    const float* b0 = (const float*)d_in[4];
    const float* b1 = (const float*)d_in[5];
    const float* b2 = (const float*)d_in[6];
    const float* b3 = (const float*)d_in[7];
    const float* H0 = (const float*)d_in[8];
    const float* H1 = (const float*)d_in[9];
    const float* H2 = (const float*)d_in[10];
    const float* H3 = (const float*)d_in[11];
    float* out = (float*)d_out;
    float* ws  = (float*)d_ws;   // needs NW*CHN*4 = 33 KB

    weights_kernel<<<1, CHN, 0, stream>>>(a0, a1, a2, b0, b1, b2, b3,
                                          H0, H1, H2, H3, ws);
    density_kernel<<<NBLOCKS, CHN, 0, stream>>>(x, ws, out);
}